// Round 11
// baseline (299.882 us; speedup 1.0000x reference)
//
#include <hip/hip_runtime.h>

// RGAT: 2-layer, 2-relation GAT. N=20000, E=320000/rel, D=128, H=2.
// Round 22: z stored as FP16 (not bf16) and consumed in aggout via
// fma_mix-friendly code: fmaf(a, (float)half, acc) -> v_fma_mix_f32 on
// gfx950 (f16 operand converted in-register, f32 accumulate). Deletes the
// 8 unpack shifts per uint4 in aggout's gather (16->8 VALU) with ZERO extra
// memory traffic; fp16 is MORE precise than bf16 for z's O(1-10) range.
// Round 21 = 297.9us, aggout 48.3 (VALU ~80%, FETCH 140MB).

#define NN 20000
#define NE 320000
#define LOG2E 1.44269504f
#define NB 79              // ceil(NN/256)

typedef unsigned short bf16_t;
typedef __attribute__((ext_vector_type(8))) short short8;
typedef __attribute__((ext_vector_type(4))) float f32x4;
typedef __attribute__((ext_vector_type(2))) _Float16 half2_t;

__device__ __forceinline__ float bf2f(bf16_t u) {
    return __uint_as_float(((unsigned)u) << 16);
}
__device__ __forceinline__ bf16_t f2bf(float f) {
    unsigned x = __float_as_uint(f);
    unsigned r = (x + 0x7fffu + ((x >> 16) & 1u)) >> 16;   // RNE
    return (bf16_t)r;
}
__device__ __forceinline__ unsigned pk2bf(float a, float b) {
    return (unsigned)f2bf(a) | ((unsigned)f2bf(b) << 16);
}
__device__ __forceinline__ float lrelu(float v) {
    return (v > 0.f) ? v : 0.2f * v;
}
__device__ __forceinline__ void load_x2(const void* x, int flag, int idx,
                                        float& v0, float& v1) {
    if (flag) {
        float2 f = ((const float2*)x)[idx];
        v0 = f.x; v1 = f.y;
    } else {
        unsigned pk = ((const unsigned*)x)[idx];
        v0 = bf2f((bf16_t)(pk & 0xffffu));
        v1 = bf2f((bf16_t)(pk >> 16));
    }
}

// ------------- convert 16 float tensors (weights) to bf16 + zero region -----
#define NTC 16
struct CzArgs {
    const void* src[NTC];
    bf16_t* dst[NTC];
    int n[NTC];
    int nblk[NTC + 1];
    int* zero_ptr;
    int zn;
    const unsigned* xsrc;
    int* flag_out;
};
__global__ void convzero_kernel(CzArgs a) {
    __shared__ int fl_s;
    int t = threadIdx.x;
    if (t < 64) {
        float mx = 0.f;
        for (int i = t; i < 256; i += 64) {
            float v = fabsf(bf2f((bf16_t)(a.xsrc[i] & 0xffffu)));
            v = (v <= 1e30f) ? v : 1e30f;
            mx = fmaxf(mx, v);
        }
        for (int off = 32; off > 0; off >>= 1) mx = fmaxf(mx, __shfl_xor(mx, off));
        if (t == 0) {
            int f = (mx > 1e6f) ? 1 : 0;
            fl_s = f;
            if (blockIdx.x == 0) *a.flag_out = f;
        }
    }
    __syncthreads();
    int flag = fl_s;
    int b = blockIdx.x;
    int ti = 0;
#pragma unroll 1
    for (; ti <= NTC; ++ti) {
        if (b < a.nblk[ti]) break;
        b -= a.nblk[ti];
    }
    int i = b * 256 + t;
    if (ti < NTC) {
        if (i < a.n[ti]) {
            if (flag) a.dst[ti][i] = f2bf(((const float*)a.src[ti])[i]);
            else      a.dst[ti][i] = ((const bf16_t*)a.src[ti])[i];
        }
    } else {
        if (i < a.zn) a.zero_ptr[i] = 0;
    }
}

// ---------------- prep: wal/war vectors, biases, frag repacks ----------------
struct PrepArgs {
    const bf16_t *W1[2], *W2[2];
    const bf16_t *al1[2], *ar1[2], *al2[2], *ar2[2];
    const bf16_t *b1[2], *b2[2];
    float *wal1, *war1;     // [2rel*2h*128], scaled by log2(e)
    float *wal2, *war2;     // [2rel*2h*256], scaled by log2(e)
    float *bc1, *bc2;       // [256], [128]
    bf16_t *Wc1f;           // combined layer-1 weight, frag order (K=512,M=256)
    bf16_t *Wzf;            // per-rel 0.5*W2 frag tables (K=256,M=256) x2
};
// bx: [0,4) wal1/war1 | [4,12) wal2/war2 | [12,14) bc | [14,78) Wc1f | [78,142) Wzf
__device__ __forceinline__ void prep_body(const PrepArgs& p, int bx, int tid) {
    if (bx < 4) {
        int t = bx * 256 + tid;
        int lr = t >> 9, rel = (t >> 8) & 1, h = (t >> 7) & 1, k = t & 127;
        const bf16_t* av = lr ? p.ar1[rel] : p.al1[rel];
        const bf16_t* W = p.W1[rel];
        float s = 0.f;
        for (int o = 0; o < 256; ++o)
            s += bf2f(W[k * 512 + h * 256 + o]) * bf2f(av[h * 256 + o]);
        (lr ? p.war1 : p.wal1)[(rel * 2 + h) * 128 + k] = s * LOG2E;
    } else if (bx < 12) {
        int t = (bx - 4) * 256 + tid;
        int lr = t >> 10, rel = (t >> 9) & 1, h = (t >> 8) & 1, k = t & 255;
        const bf16_t* av = lr ? p.ar2[rel] : p.al2[rel];
        const bf16_t* W = p.W2[rel];
        float s = 0.f;
        for (int o = 0; o < 128; ++o)
            s += bf2f(W[k * 256 + h * 128 + o]) * bf2f(av[h * 128 + o]);
        (lr ? p.war2 : p.wal2)[(rel * 2 + h) * 256 + k] = s * LOG2E;
    } else if (bx < 14) {
        int t = (bx - 12) * 256 + tid;
        if (t < 256) {
            p.bc1[t] = 0.5f * (bf2f(p.b1[0][t]) + bf2f(p.b1[0][256 + t]) +
                               bf2f(p.b1[1][t]) + bf2f(p.b1[1][256 + t]));
        } else if (t < 384) {
            int o = t - 256;
            p.bc2[o] = 0.5f * (bf2f(p.b2[0][o]) + bf2f(p.b2[0][128 + o]) +
                               bf2f(p.b2[1][o]) + bf2f(p.b2[1][128 + o]));
        }
    } else if (bx < 78) {               // Wc1f: K=512, M=256, KS=16
        int i = (bx - 14) * 256 + tid;
        int lane = i & 63;
        int t2 = i >> 6;
        int ct = t2 >> 4, ks = t2 & 15;
        int col = ct * 16 + (lane & 15);
        bf16_t* out = p.Wc1f + (size_t)i * 8;
#pragma unroll
        for (int j = 0; j < 8; ++j) {
            int r = ks * 32 + ((lane >> 4) << 3) + j;
            int rel = r >> 8, h = (r >> 7) & 1, kx = r & 127;
            out[j] = f2bf(0.5f * bf2f(p.W1[rel][kx * 512 + h * 256 + col]));
        }
    } else {                            // Wzf: per rel K=256, M=256, KS=8
        int b = bx - 78;
        int rel = b >> 5;
        int i = (b & 31) * 256 + tid;
        int lane = i & 63;
        int t2 = i >> 6;
        int ct = t2 >> 3, ks = t2 & 7;
        int col = ct * 16 + (lane & 15);
        bf16_t* out = p.Wzf + (size_t)rel * 65536 + (size_t)i * 8;
#pragma unroll
        for (int j = 0; j < 8; ++j) {
            int r = ks * 32 + ((lane >> 4) << 3) + j;
            out[j] = f2bf(0.5f * bf2f(p.W2[rel][r * 256 + col]));
        }
    }
}

// ---------------- CSR build ----------------
struct Csr2 {
    const int* src[2];
    const int* dst[2];
    int* cnt[2];     // [NN]
    int* offs[2];    // [NN+1]
    int* rank[2];    // [NE]
    int* srcc[2];    // [NE]
    int* npfx[2];    // [NN]  in-block exclusive prefix
    int* bsum[2];    // [NB]  block sums -> exclusive bases
};
struct PhArgs { PrepArgs p; Csr2 c; };
__global__ void prep_hist_kernel(PhArgs a) {
    int bx = blockIdx.x;
    if (bx < 142) {
        prep_body(a.p, bx, threadIdx.x);
    } else {
        int b = bx - 142;
        int rel = b / 1250;
        int i = (b - rel * 1250) * 256 + threadIdx.x;
        if (i < NE)
            a.c.rank[rel][i] = atomicAdd(&a.c.cnt[rel][a.c.dst[rel][i]], 1);
    }
}

// -------- hierarchical coalesced scan: blk -> top -> fin --------------------
__global__ void scan_blk_kernel(Csr2 c) {
    int rel = blockIdx.y;
    int t = threadIdx.x;
    int i = blockIdx.x * 256 + t;
    int tot = (i < NN) ? c.cnt[rel][i] : 0;
    __shared__ int sh[256];
    sh[t] = tot;
    __syncthreads();
    for (int off = 1; off < 256; off <<= 1) {
        int v = (t >= off) ? sh[t - off] : 0;
        __syncthreads();
        sh[t] += v;
        __syncthreads();
    }
    if (i < NN) c.npfx[rel][i] = sh[t] - tot;
    if (t == 255) c.bsum[rel][blockIdx.x] = sh[255];
}

__global__ void scan_top_kernel(Csr2 c) {
    int rel = blockIdx.x;
    int t = threadIdx.x;           // 128 threads
    __shared__ int sh[128];
    int v = (t < NB) ? c.bsum[rel][t] : 0;
    sh[t] = v;
    __syncthreads();
    for (int off = 1; off < 128; off <<= 1) {
        int u = (t >= off) ? sh[t - off] : 0;
        __syncthreads();
        sh[t] += u;
        __syncthreads();
    }
    if (t < NB) c.bsum[rel][t] = sh[t] - v;   // exclusive block base
    if (t == 0) c.offs[rel][NN] = NE;
}

__global__ void scan_fin_kernel(Csr2 c) {
    int rel = blockIdx.y;
    int i = blockIdx.x * 256 + threadIdx.x;
    if (i < NN)
        c.offs[rel][i] = c.bsum[rel][blockIdx.x] + c.npfx[rel][i];
}

// merged: elr1 (5000 blocks, dual-path x) + atomic-free scatter (2x313 blocks)
__global__ void scat_elr_kernel(Csr2 c, const void* __restrict__ x,
                                const int* __restrict__ flagp,
                                const float* __restrict__ wal1,
                                const float* __restrict__ war1,
                                float* __restrict__ el0, float* __restrict__ er0,
                                float* __restrict__ el1, float* __restrict__ er1) {
    __shared__ float wl[512], wr[512];
    int t = threadIdx.x;
    if (blockIdx.x < 5000) {
        wl[t] = wal1[t]; wl[t + 256] = wal1[t + 256];
        wr[t] = war1[t]; wr[t + 256] = war1[t + 256];
        __syncthreads();
        int fl = *flagp;
        int w = t >> 6, lane = t & 63;
        int node = blockIdx.x * 4 + w;
        float v0, v1;
        load_x2(x, fl, node * 64 + lane, v0, v1);
        float de[4], dr[4];
#pragma unroll
        for (int cch = 0; cch < 4; ++cch) {
            de[cch] = v0 * wl[cch * 128 + 2 * lane] + v1 * wl[cch * 128 + 2 * lane + 1];
            dr[cch] = v0 * wr[cch * 128 + 2 * lane] + v1 * wr[cch * 128 + 2 * lane + 1];
        }
#pragma unroll
        for (int off = 32; off > 0; off >>= 1) {
#pragma unroll
            for (int cch = 0; cch < 4; ++cch) {
                de[cch] += __shfl_xor(de[cch], off);
                dr[cch] += __shfl_xor(dr[cch], off);
            }
        }
        if (lane == 0) {
            el0[node * 2 + 0] = de[0]; el0[node * 2 + 1] = de[1];
            el1[node * 2 + 0] = de[2]; el1[node * 2 + 1] = de[3];
            er0[node * 2 + 0] = dr[0]; er0[node * 2 + 1] = dr[1];
            er1[node * 2 + 0] = dr[2]; er1[node * 2 + 1] = dr[3];
        }
    } else {
        int b = blockIdx.x - 5000;
        int rel = b / 313;
        int base = (b - rel * 313) * 1024 + t * 4;
        const int* dstp = c.dst[rel];
        const int* srcp = c.src[rel];
        const int* rkp  = c.rank[rel];
        const int* offp = c.offs[rel];
        int* sc = c.srcc[rel];
        if (base + 3 < NE) {
            int4 dv = *(const int4*)(dstp + base);
            int4 rv = *(const int4*)(rkp + base);
            int4 sv = *(const int4*)(srcp + base);
            sc[offp[dv.x] + rv.x] = sv.x;
            sc[offp[dv.y] + rv.y] = sv.y;
            sc[offp[dv.z] + rv.z] = sv.z;
            sc[offp[dv.w] + rv.w] = sv.w;
        } else {
            for (int k = 0; k < 4 && base + k < NE; ++k)
                sc[offp[dstp[base + k]] + rkp[base + k]] = srcp[base + k];
        }
    }
}

// ---- per-wave online softmax for one relation (both heads per lane) --------
// Logits are in log2 domain (wal/war pre-scaled); exps are bare exp2f.
// Butterfly early-exits at ceil_pow2(min(deg,64)) levels (deg wave-uniform;
// lanes >= deg end with garbage m/s but their alphas are never read).
__device__ __forceinline__ void wave_softmax(
    const int* __restrict__ srcc, int beg, int deg,
    const float* __restrict__ el, float er_h0, float er_h1, int lane,
    int& sreg, float& a0, float& a1,
    float& m0, float& i0, float& m1, float& i1) {
    float mm0 = -1e30f, ss0 = 0.f, mm1 = -1e30f, ss1 = 0.f;
    float e0r = 0.f, e1r = 0.f;
    sreg = 0;
    for (int j = lane; j < deg; j += 64) {
        int s = srcc[beg + j];
        float2 ev = ((const float2*)el)[s];
        float e0 = lrelu(ev.x + er_h0);
        float e1 = lrelu(ev.y + er_h1);
        if (j < 64) { sreg = s; e0r = e0; e1r = e1; }
        float mn0 = fmaxf(mm0, e0);
        ss0 = ss0 * exp2f(mm0 - mn0) + exp2f(e0 - mn0);
        mm0 = mn0;
        float mn1 = fmaxf(mm1, e1);
        ss1 = ss1 * exp2f(mm1 - mn1) + exp2f(e1 - mn1);
        mm1 = mn1;
    }
    int dc = min(deg, 64);
    int dpow = (dc <= 1) ? dc : (1 << (32 - __clz(dc - 1)));
#pragma unroll
    for (int off = 1; off < 64; off <<= 1) {
        if (off >= dpow) break;
        float om = __shfl_xor(mm0, off), os = __shfl_xor(ss0, off);
        float mn = fmaxf(mm0, om);
        ss0 = ss0 * exp2f(mm0 - mn) + os * exp2f(om - mn);
        mm0 = mn;
        om = __shfl_xor(mm1, off); os = __shfl_xor(ss1, off);
        mn = fmaxf(mm1, om);
        ss1 = ss1 * exp2f(mm1 - mn) + os * exp2f(om - mn);
        mm1 = mn;
    }
    m0 = mm0; m1 = mm1;
    i0 = 1.f / fmaxf(ss0, 1e-9f);
    i1 = 1.f / fmaxf(ss1, 1e-9f);
    a0 = exp2f(e0r - m0) * i0;
    a1 = exp2f(e1r - m1) * i1;
}

// ---------------- agg1: softmax + gather x rows -> y1[N,512] ----------------
// One wave per (dst node, relation). Half-wave slots, 2-deep unroll, uniform
// trip count (all shfls at full EXEC).
__global__ void agg1_kernel(
    const int* __restrict__ offs0, const int* __restrict__ srcc0,
    const float* __restrict__ el0, const float* __restrict__ er0,
    const int* __restrict__ offs1, const int* __restrict__ srcc1,
    const float* __restrict__ el1, const float* __restrict__ er1,
    const void* __restrict__ x, const int* __restrict__ flagp,
    bf16_t* __restrict__ y1) {
    int t = threadIdx.x;
    int w = t >> 6, lane = t & 63;
    int slot = lane >> 5, m = lane & 31;
    int d = blockIdx.x * 2 + (w >> 1);
    int rel = w & 1;
    const int* offs = rel ? offs1 : offs0;
    const int* srcc = rel ? srcc1 : srcc0;
    const float* el = rel ? el1 : el0;
    const float* er = rel ? er1 : er0;
    int beg = offs[d], deg = offs[d + 1] - beg;
    float erh0 = er[d * 2], erh1 = er[d * 2 + 1];
    int fl = *flagp;

    int sr;
    float a0, a1, m0, i0, m1, i1;
    wave_softmax(srcc, beg, deg, el, erh0, erh1, lane, sr, a0, a1, m0, i0, m1, i1);

    auto xload = [&](int s, float v[4]) {
        if (fl) {
            float4 f = ((const float4*)x)[s * 32 + m];
            v[0] = f.x; v[1] = f.y; v[2] = f.z; v[3] = f.w;
        } else {
            uint2 pk = ((const uint2*)x)[s * 32 + m];
            v[0] = bf2f((bf16_t)(pk.x & 0xffffu));
            v[1] = bf2f((bf16_t)(pk.x >> 16));
            v[2] = bf2f((bf16_t)(pk.y & 0xffffu));
            v[3] = bf2f((bf16_t)(pk.y >> 16));
        }
    };
    float h0[4] = {}, h1[4] = {};   // head0/head1 x 4 cols
    {
        int dm = min(deg, 64);
        int T = (dm + 3) & ~3;
        for (int jj = slot; jj < T; jj += 4) {
            int j2 = jj + 2;
            int sA = __shfl(sr, jj), sB = __shfl(sr, j2);
            float pA0 = __shfl(a0, jj), pA1 = __shfl(a1, jj);
            float pB0 = __shfl(a0, j2), pB1 = __shfl(a1, j2);
            if (jj >= dm) { sA = 0; pA0 = 0.f; pA1 = 0.f; }
            if (j2 >= dm) { sB = 0; pB0 = 0.f; pB1 = 0.f; }
            float vA[4], vB[4];
            xload(sA, vA);
            xload(sB, vB);
#pragma unroll
            for (int k = 0; k < 4; ++k) {
                h0[k] += pA0 * vA[k] + pB0 * vB[k];
                h1[k] += pA1 * vA[k] + pB1 * vB[k];
            }
        }
        for (int jj = 64 + slot; jj < deg; jj += 2) {       // rare: deg > 64
            int sA = srcc[beg + jj];
            float2 ev = ((const float2*)el)[sA];
            float pA0 = exp2f(lrelu(ev.x + erh0) - m0) * i0;
            float pA1 = exp2f(lrelu(ev.y + erh1) - m1) * i1;
            float vA[4];
            xload(sA, vA);
#pragma unroll
            for (int k = 0; k < 4; ++k) {
                h0[k] += pA0 * vA[k];
                h1[k] += pA1 * vA[k];
            }
        }
    }
#pragma unroll
    for (int k = 0; k < 4; ++k) {
        h0[k] += __shfl_xor(h0[k], 32);
        h1[k] += __shfl_xor(h1[k], 32);
    }
    if (slot == 0) {
        bf16_t* yr = y1 + (size_t)d * 512 + rel * 256;
        uint2 u;
        u.x = pk2bf(h0[0], h0[1]); u.y = pk2bf(h0[2], h0[3]);
        ((uint2*)yr)[m] = u;
        u.x = pk2bf(h1[0], h1[1]); u.y = pk2bf(h1[2], h1[3]);
        ((uint2*)(yr + 128))[m] = u;
    }
}

// -------- gemm1: h1 = relu(y1 @ Wc1 + bc1); 8 col-frags/wave; el2/er2 -------
__global__ void gemm1_kernel(const bf16_t* __restrict__ A, const bf16_t* __restrict__ Wf,
                             const float* __restrict__ bc1, bf16_t* __restrict__ h1,
                             const float* __restrict__ wal2, const float* __restrict__ war2,
                             float* __restrict__ el2_0, float* __restrict__ er2_0,
                             float* __restrict__ el2_1, float* __restrict__ er2_1,
                             int n) {
    constexpr int K = 512, M = 256, KS = 16, NF = 8;
    int w = threadIdx.x >> 6, lane = threadIdx.x & 63;
    int q = lane >> 4, m16 = lane & 15;
    int rf = blockIdx.y * 64 + w * 16;
    if (rf >= n) return;
    f32x4 acc[NF] = {};
    const bf16_t* Arow = A + (size_t)(rf + m16) * K + q * 8;
    for (int ks = 0; ks < KS; ++ks) {
        short8 af = *(const short8*)(Arow + ks * 32);
#pragma unroll
        for (int f = 0; f < NF; ++f) {
            int ct = blockIdx.x * NF + f;
            short8 bfr = *(const short8*)(Wf + ((size_t)(ct * KS + ks) * 64 + lane) * 8);
            acc[f] = __builtin_amdgcn_mfma_f32_16x16x32_bf16(af, bfr, acc[f], 0, 0, 0);
        }
    }
    int col0 = blockIdx.x * (NF * 16);
    float del[2][2][4] = {};
    float der[2][2][4] = {};
#pragma unroll
    for (int f = 0; f < NF; ++f) {
        int col = col0 + f * 16 + m16;
        float bcv = bc1[col];
        float wle[2][2], wre[2][2];
#pragma unroll
        for (int rel = 0; rel < 2; ++rel)
#pragma unroll
            for (int h = 0; h < 2; ++h) {
                wle[rel][h] = wal2[(rel * 2 + h) * 256 + col];
                wre[rel][h] = war2[(rel * 2 + h) * 256 + col];
            }
#pragma unroll
        for (int r = 0; r < 4; ++r) {
            int row = rf + q * 4 + r;
            float v = fmaxf(acc[f][r] + bcv, 0.f);
            bf16_t hb = f2bf(v);
            h1[(size_t)row * M + col] = hb;
            float vb = bf2f(hb);
#pragma unroll
            for (int rel = 0; rel < 2; ++rel)
#pragma unroll
                for (int h = 0; h < 2; ++h) {
                    del[rel][h][r] += vb * wle[rel][h];
                    der[rel][h][r] += vb * wre[rel][h];
                }
        }
    }
#pragma unroll
    for (int off = 1; off < 16; off <<= 1) {
#pragma unroll
        for (int rel = 0; rel < 2; ++rel)
#pragma unroll
            for (int h = 0; h < 2; ++h)
#pragma unroll
                for (int r = 0; r < 4; ++r) {
                    del[rel][h][r] += __shfl_xor(del[rel][h][r], off);
                    der[rel][h][r] += __shfl_xor(der[rel][h][r], off);
                }
    }
    if (m16 == 0) {
#pragma unroll
        for (int r = 0; r < 4; ++r) {
            int row = rf + q * 4 + r;
            atomicAdd(&el2_0[row * 2 + 0], del[0][0][r]);
            atomicAdd(&el2_0[row * 2 + 1], del[0][1][r]);
            atomicAdd(&el2_1[row * 2 + 0], del[1][0][r]);
            atomicAdd(&el2_1[row * 2 + 1], del[1][1][r]);
            atomicAdd(&er2_0[row * 2 + 0], der[0][0][r]);
            atomicAdd(&er2_0[row * 2 + 1], der[0][1][r]);
            atomicAdd(&er2_1[row * 2 + 0], der[1][0][r]);
            atomicAdd(&er2_1[row * 2 + 1], der[1][1][r]);
        }
    }
}

// -------- gemmZ: z_rel = h1 @ (0.5*W2_rel); fp16 output ---------------------
__global__ void gemmz_kernel(const bf16_t* __restrict__ A, const bf16_t* __restrict__ Wzf,
                             _Float16* __restrict__ z, int n) {
    constexpr int K = 256, M = 256, KS = 8, NF = 8;
    int rel = blockIdx.z;
    const bf16_t* Wf = Wzf + (size_t)rel * 65536;
    _Float16* C = z + (size_t)rel * NN * 256;
    int w = threadIdx.x >> 6, lane = threadIdx.x & 63;
    int q = lane >> 4, m16 = lane & 15;
    int rf = blockIdx.y * 64 + w * 16;
    if (rf >= n) return;
    f32x4 acc[NF] = {};
    const bf16_t* Arow = A + (size_t)(rf + m16) * K + q * 8;
    for (int ks = 0; ks < KS; ++ks) {
        short8 af = *(const short8*)(Arow + ks * 32);
#pragma unroll
        for (int f = 0; f < NF; ++f) {
            int ct = blockIdx.x * NF + f;
            short8 bfr = *(const short8*)(Wf + ((size_t)(ct * KS + ks) * 64 + lane) * 8);
            acc[f] = __builtin_amdgcn_mfma_f32_16x16x32_bf16(af, bfr, acc[f], 0, 0, 0);
        }
    }
    int col0 = blockIdx.x * (NF * 16);
#pragma unroll
    for (int f = 0; f < NF; ++f) {
#pragma unroll
        for (int r = 0; r < 4; ++r) {
            int row = rf + q * 4 + r;
            C[(size_t)row * M + col0 + f * 16 + m16] = (_Float16)acc[f][r];
        }
    }
}

// -------- aggout: softmax + gather fp16 z rows -> out[N,128] ----------------
// One wave per (dst node, relation). Half-wave (32 lanes x 8 cols, uint4)
// row gather; fp16 z consumed via fmaf(a,(float)h,acc) -> v_fma_mix_f32.
// rel0+rel1 combined via 2KB LDS + one barrier per 2-node block.
__global__ void aggout_kernel(
    const int* __restrict__ offs0, const int* __restrict__ srcc0,
    const float* __restrict__ el0, const float* __restrict__ er0,
    const int* __restrict__ offs1, const int* __restrict__ srcc1,
    const float* __restrict__ el1, const float* __restrict__ er1,
    const _Float16* __restrict__ z, const float* __restrict__ bc2,
    void* __restrict__ out, const int* __restrict__ flagp) {
    __shared__ float sh[4][128];
    int t = threadIdx.x;
    int w = t >> 6, lane = t & 63;
    int slot = lane >> 5, m = lane & 31;
    int h = m >> 4;
    int d = blockIdx.x * 2 + (w >> 1);
    int rel = w & 1;
    const int* offs = rel ? offs1 : offs0;
    const int* srcc = rel ? srcc1 : srcc0;
    const float* el = rel ? el1 : el0;
    const float* er = rel ? er1 : er0;
    int beg = offs[d], deg = offs[d + 1] - beg;
    float erh0 = er[d * 2], erh1 = er[d * 2 + 1];

    int sr;
    float a0, a1, m0, i0, m1, i1;
    wave_softmax(srcc, beg, deg, el, erh0, erh1, lane, sr, a0, a1, m0, i0, m1, i1);

    float acc[8] = {};
    auto fmadd8 = [&](float a, uint4 p) {
        half2_t h0v = __builtin_bit_cast(half2_t, p.x);
        half2_t h1v = __builtin_bit_cast(half2_t, p.y);
        half2_t h2v = __builtin_bit_cast(half2_t, p.z);
        half2_t h3v = __builtin_bit_cast(half2_t, p.w);
        acc[0] = fmaf(a, (float)h0v.x, acc[0]);
        acc[1] = fmaf(a, (float)h0v.y, acc[1]);
        acc[2] = fmaf(a, (float)h1v.x, acc[2]);
        acc[3] = fmaf(a, (float)h1v.y, acc[3]);
        acc[4] = fmaf(a, (float)h2v.x, acc[4]);
        acc[5] = fmaf(a, (float)h2v.y, acc[5]);
        acc[6] = fmaf(a, (float)h3v.x, acc[6]);
        acc[7] = fmaf(a, (float)h3v.y, acc[7]);
    };
    {
        const uint4* zp = (const uint4*)(z + (size_t)rel * NN * 256);
        int dm = min(deg, 64);
        int T = (dm + 3) & ~3;
        for (int jj = slot; jj < T; jj += 4) {
            int j2 = jj + 2;
            int sA = __shfl(sr, jj), sB = __shfl(sr, j2);
            float xA0 = __shfl(a0, jj), xA1 = __shfl(a1, jj);
            float xB0 = __shfl(a0, j2), xB1 = __shfl(a1, j2);
            float aA = h ? xA1 : xA0;
            float aB = h ? xB1 : xB0;
            if (jj >= dm) { sA = 0; aA = 0.f; }
            if (j2 >= dm) { sB = 0; aB = 0.f; }
            uint4 pA = zp[sA * 32 + m];
            uint4 pB = zp[sB * 32 + m];
            fmadd8(aA, pA);
            fmadd8(aB, pB);
        }
        for (int jj = 64 + slot; jj < deg; jj += 2) {       // rare: deg > 64
            int sA = srcc[beg + jj];
            float2 ev = ((const float2*)el)[sA];
            float aA = h ? (exp2f(lrelu(ev.y + erh1) - m1) * i1)
                         : (exp2f(lrelu(ev.x + erh0) - m0) * i0);
            uint4 pA = zp[sA * 32 + m];
            fmadd8(aA, pA);
        }
    }
    // combine edge slots, then heads: lane m<16 of slot0 holds cols m*8..m*8+7
#pragma unroll
    for (int k = 0; k < 8; ++k) acc[k] += __shfl_xor(acc[k], 32);
#pragma unroll
    for (int k = 0; k < 8; ++k) acc[k] += __shfl_xor(acc[k], 16);
    if (slot == 0 && m < 16) {
#pragma unroll
        for (int k = 0; k < 8; ++k) sh[w][m * 8 + k] = acc[k];
    }
    __syncthreads();
    // 256 threads: t<128 -> node 0 of the pair, t>=128 -> node 1
    int ni = t >> 7;
    int o = t & 127;
    int dd = blockIdx.x * 2 + ni;
    float v = bc2[o] + sh[ni * 2][o] + sh[ni * 2 + 1][o];
    if (*flagp) ((float*)out)[(size_t)dd * 128 + o] = v;
    else        ((bf16_t*)out)[(size_t)dd * 128 + o] = f2bf(v);
}

extern "C" void kernel_launch(void* const* d_in, const int* in_sizes, int n_in,
                              void* d_out, int out_size, void* d_ws, size_t ws_size,
                              hipStream_t stream) {
    (void)in_sizes; (void)n_in; (void)out_size; (void)ws_size;
    const void* x0 = d_in[0];
    const int* src0 = (const int*)d_in[1];
    const int* dst0 = (const int*)d_in[2];
    const int* src1 = (const int*)d_in[3];
    const int* dst1 = (const int*)d_in[4];

    char* ws = (char*)d_ws;
    size_t off = 0;
    auto alloc = [&](size_t bytes) -> void* {
        void* p = ws + off;
        off = (off + bytes + 255) & ~(size_t)255;
        return p;
    };
    int* flag = (int*)alloc(4);
    static const int tn[NTC] = {128 * 512, 512, 512, 512,
                                128 * 512, 512, 512, 512,
                                256 * 256, 256, 256, 256,
                                256 * 256, 256, 256, 256};
    bf16_t* tb[NTC];
    for (int i = 0; i < NTC; ++i) tb[i] = (bf16_t*)alloc((size_t)tn[i] * 2);

    bf16_t* Wc1f = (bf16_t*)alloc((size_t)512 * 256 * 2);
    bf16_t* Wzf  = (bf16_t*)alloc((size_t)2 * 65536 * 2);
    float* wal1 = (float*)alloc(512 * 4);
    float* war1 = (float*)alloc(512 * 4);
    float* wal2 = (float*)alloc(1024 * 4);
    float* war2 = (float*)alloc(1024 * 4);
    float* bc1  = (float*)alloc(256 * 4);
    float* bc2  = (float*)alloc(128 * 4);

    char* zbeg = ws + off;
    int* cnt0 = (int*)alloc(NN * 4);
    int* cnt1 = (int*)alloc(NN * 4);
    float* el2_0 = (float*)alloc(NN * 2 * 4);
    float* er2_0 = (float*)alloc(NN * 2 * 4);
    float* el2_1 = (float*)alloc(NN * 2 * 4);
    float* er2_1 = (float*)alloc(NN * 2 * 4);
    char* zend = ws + off;
    int zcount = (int)((zend - zbeg) >> 2);

    int* offs0 = (int*)alloc((NN + 1) * 4);
    int* offs1 = (int*)alloc((NN + 1) * 4);
    int* npfx0 = (int*)alloc(NN * 4);
    int* npfx1 = (int*)alloc(NN * 4);
    int* bsum0 = (int*)alloc(128 * 4);
    int* bsum1 = (int*)alloc(128 * 4);
    int* rank0 = (int*)alloc(NE * 4);
    int* rank1 = (int*)alloc(NE * 4);
    int* srcc0 = (int*)alloc(NE * 4);
    int* srcc1 = (int*)alloc(NE * 4);
    float* el1_0 = (float*)alloc(NN * 2 * 4);
    float* er1_0 = (float*)alloc(NN * 2 * 4);
    float* el1_1 = (float*)alloc(NN * 2 * 4);
    float* er1_1 = (float*)alloc(NN * 2 * 4);
    bf16_t* h1 = (bf16_t*)alloc((size_t)NN * 256 * 2);
    bf16_t* Y  = (bf16_t*)alloc((size_t)NN * 1024 * 2);  // y1 [N,512]; later z [2][N,256] fp16
    bf16_t* y1 = Y;
    _Float16* z = (_Float16*)Y;   // safe: gemmZ writes z after gemm1 finished reading y1

    // ---- 1. convert weights + zero + inline dtype detect ----
    CzArgs cz;
    static const int din_idx[NTC] = {5, 6, 7, 8, 9, 10, 11, 12,
                                     13, 14, 15, 16, 17, 18, 19, 20};
    int total_blocks = 0;
    for (int i = 0; i < NTC; ++i) {
        cz.src[i] = d_in[din_idx[i]];
        cz.dst[i] = tb[i];
        cz.n[i] = tn[i];
        cz.nblk[i] = (tn[i] + 255) / 256;
        total_blocks += cz.nblk[i];
    }
    cz.zero_ptr = (int*)zbeg;
    cz.zn = zcount;
    cz.nblk[NTC] = (zcount + 255) / 256;
    total_blocks += cz.nblk[NTC];
    cz.xsrc = (const unsigned*)x0;
    cz.flag_out = flag;
    convzero_kernel<<<total_blocks, 256, 0, stream>>>(cz);

    // ---- 2. prep + hist (hist stores rank = atomic return) ----
    PhArgs ph;
    ph.p.W1[0] = tb[0];  ph.p.W1[1] = tb[4];
    ph.p.W2[0] = tb[8];  ph.p.W2[1] = tb[12];
    ph.p.al1[0] = tb[1]; ph.p.ar1[0] = tb[2];
    ph.p.al1[1] = tb[5]; ph.p.ar1[1] = tb[6];
    ph.p.al2[0] = tb[9]; ph.p.ar2[0] = tb[10];
    ph.p.al2[1] = tb[13]; ph.p.ar2[1] = tb[14];
    ph.p.b1[0] = tb[3];  ph.p.b1[1] = tb[7];
    ph.p.b2[0] = tb[11]; ph.p.b2[1] = tb[15];
    ph.p.wal1 = wal1; ph.p.war1 = war1;
    ph.p.wal2 = wal2; ph.p.war2 = war2;
    ph.p.bc1 = bc1; ph.p.bc2 = bc2;
    ph.p.Wc1f = Wc1f; ph.p.Wzf = Wzf;
    ph.c.src[0] = src0; ph.c.src[1] = src1;
    ph.c.dst[0] = dst0; ph.c.dst[1] = dst1;
    ph.c.cnt[0] = cnt0; ph.c.cnt[1] = cnt1;
    ph.c.offs[0] = offs0; ph.c.offs[1] = offs1;
    ph.c.rank[0] = rank0; ph.c.rank[1] = rank1;
    ph.c.srcc[0] = srcc0; ph.c.srcc[1] = srcc1;
    ph.c.npfx[0] = npfx0; ph.c.npfx[1] = npfx1;
    ph.c.bsum[0] = bsum0; ph.c.bsum[1] = bsum1;
    prep_hist_kernel<<<142 + 2500, 256, 0, stream>>>(ph);

    // ---- 3. hierarchical coalesced scan ----
    scan_blk_kernel<<<dim3(NB, 2), 256, 0, stream>>>(ph.c);
    scan_top_kernel<<<2, 128, 0, stream>>>(ph.c);
    scan_fin_kernel<<<dim3(NB, 2), 256, 0, stream>>>(ph.c);

    // ---- 4. elr1 + atomic-free scatter ----
    scat_elr_kernel<<<5000 + 626, 256, 0, stream>>>(
        ph.c, x0, flag, wal1, war1, el1_0, er1_0, el1_1, er1_1);

    // ---- 5. agg1: gather x rows -> y1[N,512] ----
    agg1_kernel<<<10000, 256, 0, stream>>>(offs0, srcc0, el1_0, er1_0,
                                           offs1, srcc1, el1_1, er1_1, x0, flag, y1);

    // ---- 6. gemm1 -> h1, el2/er2 ----
    gemm1_kernel<<<dim3(2, 313), 256, 0, stream>>>(
        y1, Wc1f, bc1, h1, wal2, war2, el2_0, er2_0, el2_1, er2_1, NN);

    // ---- 7. gemmZ: z_rel = h1 @ (0.5*W2_rel), fp16 out ----
    gemmz_kernel<<<dim3(2, 313, 2), 256, 0, stream>>>(h1, Wzf, z, NN);

    // ---- 8. aggout: gather fp16 z rows -> d_out ----
    aggout_kernel<<<10000, 256, 0, stream>>>(offs0, srcc0, el2_0, er2_0,
                                             offs1, srcc1, el2_1, er2_1,
                                             z, bc2, d_out, flag);
}

// Round 12
// 286.936 us; speedup vs baseline: 1.0451x; 1.0451x over previous
//
#include <hip/hip_runtime.h>

// RGAT: 2-layer, 2-relation GAT. N=20000, E=320000/rel, D=128, H=2.
// Round 23: revert r22's fp16 z (cvt+fma didn't fuse to fma_mix; VGPR 28->32,
// -3 occ, aggout +3us). Base = r21 (297.9us best). New: elr1 restructured to
// 8 NODES PER WAVE (8 lanes x 16 cols each) — butterfly 6 levels -> 3,
// 20000 -> 2500 waves, per-lane work becomes 8 independent FMA chains
// (throughput) instead of a 48-deep serial shfl chain (latency).

#define NN 20000
#define NE 320000
#define LOG2E 1.44269504f
#define NB 79              // ceil(NN/256)

typedef unsigned short bf16_t;
typedef __attribute__((ext_vector_type(8))) short short8;
typedef __attribute__((ext_vector_type(4))) float f32x4;

__device__ __forceinline__ float bf2f(bf16_t u) {
    return __uint_as_float(((unsigned)u) << 16);
}
__device__ __forceinline__ bf16_t f2bf(float f) {
    unsigned x = __float_as_uint(f);
    unsigned r = (x + 0x7fffu + ((x >> 16) & 1u)) >> 16;   // RNE
    return (bf16_t)r;
}
__device__ __forceinline__ unsigned pk2bf(float a, float b) {
    return (unsigned)f2bf(a) | ((unsigned)f2bf(b) << 16);
}
__device__ __forceinline__ float lrelu(float v) {
    return (v > 0.f) ? v : 0.2f * v;
}
__device__ __forceinline__ void load_x2(const void* x, int flag, int idx,
                                        float& v0, float& v1) {
    if (flag) {
        float2 f = ((const float2*)x)[idx];
        v0 = f.x; v1 = f.y;
    } else {
        unsigned pk = ((const unsigned*)x)[idx];
        v0 = bf2f((bf16_t)(pk & 0xffffu));
        v1 = bf2f((bf16_t)(pk >> 16));
    }
}

// ------------- convert 16 float tensors (weights) to bf16 + zero region -----
#define NTC 16
struct CzArgs {
    const void* src[NTC];
    bf16_t* dst[NTC];
    int n[NTC];
    int nblk[NTC + 1];
    int* zero_ptr;
    int zn;
    const unsigned* xsrc;
    int* flag_out;
};
__global__ void convzero_kernel(CzArgs a) {
    __shared__ int fl_s;
    int t = threadIdx.x;
    if (t < 64) {
        float mx = 0.f;
        for (int i = t; i < 256; i += 64) {
            float v = fabsf(bf2f((bf16_t)(a.xsrc[i] & 0xffffu)));
            v = (v <= 1e30f) ? v : 1e30f;
            mx = fmaxf(mx, v);
        }
        for (int off = 32; off > 0; off >>= 1) mx = fmaxf(mx, __shfl_xor(mx, off));
        if (t == 0) {
            int f = (mx > 1e6f) ? 1 : 0;
            fl_s = f;
            if (blockIdx.x == 0) *a.flag_out = f;
        }
    }
    __syncthreads();
    int flag = fl_s;
    int b = blockIdx.x;
    int ti = 0;
#pragma unroll 1
    for (; ti <= NTC; ++ti) {
        if (b < a.nblk[ti]) break;
        b -= a.nblk[ti];
    }
    int i = b * 256 + t;
    if (ti < NTC) {
        if (i < a.n[ti]) {
            if (flag) a.dst[ti][i] = f2bf(((const float*)a.src[ti])[i]);
            else      a.dst[ti][i] = ((const bf16_t*)a.src[ti])[i];
        }
    } else {
        if (i < a.zn) a.zero_ptr[i] = 0;
    }
}

// ---------------- prep: wal/war vectors, biases, frag repacks ----------------
struct PrepArgs {
    const bf16_t *W1[2], *W2[2];
    const bf16_t *al1[2], *ar1[2], *al2[2], *ar2[2];
    const bf16_t *b1[2], *b2[2];
    float *wal1, *war1;     // [2rel*2h*128], scaled by log2(e)
    float *wal2, *war2;     // [2rel*2h*256], scaled by log2(e)
    float *bc1, *bc2;       // [256], [128]
    bf16_t *Wc1f;           // combined layer-1 weight, frag order (K=512,M=256)
    bf16_t *Wzf;            // per-rel 0.5*W2 frag tables (K=256,M=256) x2
};
// bx: [0,4) wal1/war1 | [4,12) wal2/war2 | [12,14) bc | [14,78) Wc1f | [78,142) Wzf
__device__ __forceinline__ void prep_body(const PrepArgs& p, int bx, int tid) {
    if (bx < 4) {
        int t = bx * 256 + tid;
        int lr = t >> 9, rel = (t >> 8) & 1, h = (t >> 7) & 1, k = t & 127;
        const bf16_t* av = lr ? p.ar1[rel] : p.al1[rel];
        const bf16_t* W = p.W1[rel];
        float s = 0.f;
        for (int o = 0; o < 256; ++o)
            s += bf2f(W[k * 512 + h * 256 + o]) * bf2f(av[h * 256 + o]);
        (lr ? p.war1 : p.wal1)[(rel * 2 + h) * 128 + k] = s * LOG2E;
    } else if (bx < 12) {
        int t = (bx - 4) * 256 + tid;
        int lr = t >> 10, rel = (t >> 9) & 1, h = (t >> 8) & 1, k = t & 255;
        const bf16_t* av = lr ? p.ar2[rel] : p.al2[rel];
        const bf16_t* W = p.W2[rel];
        float s = 0.f;
        for (int o = 0; o < 128; ++o)
            s += bf2f(W[k * 256 + h * 128 + o]) * bf2f(av[h * 128 + o]);
        (lr ? p.war2 : p.wal2)[(rel * 2 + h) * 256 + k] = s * LOG2E;
    } else if (bx < 14) {
        int t = (bx - 12) * 256 + tid;
        if (t < 256) {
            p.bc1[t] = 0.5f * (bf2f(p.b1[0][t]) + bf2f(p.b1[0][256 + t]) +
                               bf2f(p.b1[1][t]) + bf2f(p.b1[1][256 + t]));
        } else if (t < 384) {
            int o = t - 256;
            p.bc2[o] = 0.5f * (bf2f(p.b2[0][o]) + bf2f(p.b2[0][128 + o]) +
                               bf2f(p.b2[1][o]) + bf2f(p.b2[1][128 + o]));
        }
    } else if (bx < 78) {               // Wc1f: K=512, M=256, KS=16
        int i = (bx - 14) * 256 + tid;
        int lane = i & 63;
        int t2 = i >> 6;
        int ct = t2 >> 4, ks = t2 & 15;
        int col = ct * 16 + (lane & 15);
        bf16_t* out = p.Wc1f + (size_t)i * 8;
#pragma unroll
        for (int j = 0; j < 8; ++j) {
            int r = ks * 32 + ((lane >> 4) << 3) + j;
            int rel = r >> 8, h = (r >> 7) & 1, kx = r & 127;
            out[j] = f2bf(0.5f * bf2f(p.W1[rel][kx * 512 + h * 256 + col]));
        }
    } else {                            // Wzf: per rel K=256, M=256, KS=8
        int b = bx - 78;
        int rel = b >> 5;
        int i = (b & 31) * 256 + tid;
        int lane = i & 63;
        int t2 = i >> 6;
        int ct = t2 >> 3, ks = t2 & 7;
        int col = ct * 16 + (lane & 15);
        bf16_t* out = p.Wzf + (size_t)rel * 65536 + (size_t)i * 8;
#pragma unroll
        for (int j = 0; j < 8; ++j) {
            int r = ks * 32 + ((lane >> 4) << 3) + j;
            out[j] = f2bf(0.5f * bf2f(p.W2[rel][r * 256 + col]));
        }
    }
}

// ---------------- CSR build ----------------
struct Csr2 {
    const int* src[2];
    const int* dst[2];
    int* cnt[2];     // [NN]
    int* offs[2];    // [NN+1]
    int* rank[2];    // [NE]
    int* srcc[2];    // [NE]
    int* npfx[2];    // [NN]  in-block exclusive prefix
    int* bsum[2];    // [NB]  block sums -> exclusive bases
};
struct PhArgs { PrepArgs p; Csr2 c; };
__global__ void prep_hist_kernel(PhArgs a) {
    int bx = blockIdx.x;
    if (bx < 142) {
        prep_body(a.p, bx, threadIdx.x);
    } else {
        int b = bx - 142;
        int rel = b / 1250;
        int i = (b - rel * 1250) * 256 + threadIdx.x;
        if (i < NE)
            a.c.rank[rel][i] = atomicAdd(&a.c.cnt[rel][a.c.dst[rel][i]], 1);
    }
}

// -------- hierarchical coalesced scan: blk -> top -> fin --------------------
__global__ void scan_blk_kernel(Csr2 c) {
    int rel = blockIdx.y;
    int t = threadIdx.x;
    int i = blockIdx.x * 256 + t;
    int tot = (i < NN) ? c.cnt[rel][i] : 0;
    __shared__ int sh[256];
    sh[t] = tot;
    __syncthreads();
    for (int off = 1; off < 256; off <<= 1) {
        int v = (t >= off) ? sh[t - off] : 0;
        __syncthreads();
        sh[t] += v;
        __syncthreads();
    }
    if (i < NN) c.npfx[rel][i] = sh[t] - tot;
    if (t == 255) c.bsum[rel][blockIdx.x] = sh[255];
}

__global__ void scan_top_kernel(Csr2 c) {
    int rel = blockIdx.x;
    int t = threadIdx.x;           // 128 threads
    __shared__ int sh[128];
    int v = (t < NB) ? c.bsum[rel][t] : 0;
    sh[t] = v;
    __syncthreads();
    for (int off = 1; off < 128; off <<= 1) {
        int u = (t >= off) ? sh[t - off] : 0;
        __syncthreads();
        sh[t] += u;
        __syncthreads();
    }
    if (t < NB) c.bsum[rel][t] = sh[t] - v;   // exclusive block base
    if (t == 0) c.offs[rel][NN] = NE;
}

__global__ void scan_fin_kernel(Csr2 c) {
    int rel = blockIdx.y;
    int i = blockIdx.x * 256 + threadIdx.x;
    if (i < NN)
        c.offs[rel][i] = c.bsum[rel][blockIdx.x] + c.npfx[rel][i];
}

// merged: elr1 (625 blocks, 8 nodes/wave) + atomic-free scatter (2x313 blocks)
__global__ void scat_elr_kernel(Csr2 c, const void* __restrict__ x,
                                const int* __restrict__ flagp,
                                const float* __restrict__ wal1,
                                const float* __restrict__ war1,
                                float* __restrict__ el0, float* __restrict__ er0,
                                float* __restrict__ el1, float* __restrict__ er1) {
    __shared__ float wl[512], wr[512];
    int t = threadIdx.x;
    if (blockIdx.x < 625) {
        wl[t] = wal1[t]; wl[t + 256] = wal1[t + 256];
        wr[t] = war1[t]; wr[t + 256] = war1[t + 256];
        __syncthreads();
        int fl = *flagp;
        int w = t >> 6, lane = t & 63;
        int nsub = lane >> 3, s = lane & 7;   // 8 nodes/wave, 8 lanes/node
        int node = blockIdx.x * 32 + w * 8 + nsub;
        float v[16];                           // this lane's 16 cols
        if (fl) {
            const float4* xr = (const float4*)x + (size_t)node * 32 + s * 4;
#pragma unroll
            for (int j = 0; j < 4; ++j) {
                float4 f = xr[j];
                v[j * 4 + 0] = f.x; v[j * 4 + 1] = f.y;
                v[j * 4 + 2] = f.z; v[j * 4 + 3] = f.w;
            }
        } else {
            const uint4* xr = (const uint4*)x + (size_t)node * 16 + s * 2;
#pragma unroll
            for (int j = 0; j < 2; ++j) {
                uint4 q = xr[j];
                unsigned uu[4] = {q.x, q.y, q.z, q.w};
#pragma unroll
                for (int p2 = 0; p2 < 4; ++p2) {
                    v[j * 8 + p2 * 2 + 0] = bf2f((bf16_t)(uu[p2] & 0xffffu));
                    v[j * 8 + p2 * 2 + 1] = bf2f((bf16_t)(uu[p2] >> 16));
                }
            }
        }
        int c0 = s * 16;
        float de[4] = {}, dr[4] = {};
#pragma unroll
        for (int k = 0; k < 16; ++k) {
            float vv = v[k];
#pragma unroll
            for (int cch = 0; cch < 4; ++cch) {
                de[cch] += vv * wl[cch * 128 + c0 + k];
                dr[cch] += vv * wr[cch * 128 + c0 + k];
            }
        }
#pragma unroll
        for (int off = 1; off < 8; off <<= 1) {
#pragma unroll
            for (int cch = 0; cch < 4; ++cch) {
                de[cch] += __shfl_xor(de[cch], off);
                dr[cch] += __shfl_xor(dr[cch], off);
            }
        }
        if (s == 0) {
            el0[node * 2 + 0] = de[0]; el0[node * 2 + 1] = de[1];
            el1[node * 2 + 0] = de[2]; el1[node * 2 + 1] = de[3];
            er0[node * 2 + 0] = dr[0]; er0[node * 2 + 1] = dr[1];
            er1[node * 2 + 0] = dr[2]; er1[node * 2 + 1] = dr[3];
        }
    } else {
        int b = blockIdx.x - 625;
        int rel = b / 313;
        int base = (b - rel * 313) * 1024 + t * 4;
        const int* dstp = c.dst[rel];
        const int* srcp = c.src[rel];
        const int* rkp  = c.rank[rel];
        const int* offp = c.offs[rel];
        int* sc = c.srcc[rel];
        if (base + 3 < NE) {
            int4 dv = *(const int4*)(dstp + base);
            int4 rv = *(const int4*)(rkp + base);
            int4 sv = *(const int4*)(srcp + base);
            sc[offp[dv.x] + rv.x] = sv.x;
            sc[offp[dv.y] + rv.y] = sv.y;
            sc[offp[dv.z] + rv.z] = sv.z;
            sc[offp[dv.w] + rv.w] = sv.w;
        } else {
            for (int k = 0; k < 4 && base + k < NE; ++k)
                sc[offp[dstp[base + k]] + rkp[base + k]] = srcp[base + k];
        }
    }
}

// ---- per-wave online softmax for one relation (both heads per lane) --------
// Logits are in log2 domain (wal/war pre-scaled); exps are bare exp2f.
// Butterfly early-exits at ceil_pow2(min(deg,64)) levels (deg wave-uniform;
// lanes >= deg end with garbage m/s but their alphas are never read).
__device__ __forceinline__ void wave_softmax(
    const int* __restrict__ srcc, int beg, int deg,
    const float* __restrict__ el, float er_h0, float er_h1, int lane,
    int& sreg, float& a0, float& a1,
    float& m0, float& i0, float& m1, float& i1) {
    float mm0 = -1e30f, ss0 = 0.f, mm1 = -1e30f, ss1 = 0.f;
    float e0r = 0.f, e1r = 0.f;
    sreg = 0;
    for (int j = lane; j < deg; j += 64) {
        int s = srcc[beg + j];
        float2 ev = ((const float2*)el)[s];
        float e0 = lrelu(ev.x + er_h0);
        float e1 = lrelu(ev.y + er_h1);
        if (j < 64) { sreg = s; e0r = e0; e1r = e1; }
        float mn0 = fmaxf(mm0, e0);
        ss0 = ss0 * exp2f(mm0 - mn0) + exp2f(e0 - mn0);
        mm0 = mn0;
        float mn1 = fmaxf(mm1, e1);
        ss1 = ss1 * exp2f(mm1 - mn1) + exp2f(e1 - mn1);
        mm1 = mn1;
    }
    int dc = min(deg, 64);
    int dpow = (dc <= 1) ? dc : (1 << (32 - __clz(dc - 1)));
#pragma unroll
    for (int off = 1; off < 64; off <<= 1) {
        if (off >= dpow) break;
        float om = __shfl_xor(mm0, off), os = __shfl_xor(ss0, off);
        float mn = fmaxf(mm0, om);
        ss0 = ss0 * exp2f(mm0 - mn) + os * exp2f(om - mn);
        mm0 = mn;
        om = __shfl_xor(mm1, off); os = __shfl_xor(ss1, off);
        mn = fmaxf(mm1, om);
        ss1 = ss1 * exp2f(mm1 - mn) + os * exp2f(om - mn);
        mm1 = mn;
    }
    m0 = mm0; m1 = mm1;
    i0 = 1.f / fmaxf(ss0, 1e-9f);
    i1 = 1.f / fmaxf(ss1, 1e-9f);
    a0 = exp2f(e0r - m0) * i0;
    a1 = exp2f(e1r - m1) * i1;
}

// ---------------- agg1: softmax + gather x rows -> y1[N,512] ----------------
// One wave per (dst node, relation). Half-wave slots, 2-deep unroll, uniform
// trip count (all shfls at full EXEC).
__global__ void agg1_kernel(
    const int* __restrict__ offs0, const int* __restrict__ srcc0,
    const float* __restrict__ el0, const float* __restrict__ er0,
    const int* __restrict__ offs1, const int* __restrict__ srcc1,
    const float* __restrict__ el1, const float* __restrict__ er1,
    const void* __restrict__ x, const int* __restrict__ flagp,
    bf16_t* __restrict__ y1) {
    int t = threadIdx.x;
    int w = t >> 6, lane = t & 63;
    int slot = lane >> 5, m = lane & 31;
    int d = blockIdx.x * 2 + (w >> 1);
    int rel = w & 1;
    const int* offs = rel ? offs1 : offs0;
    const int* srcc = rel ? srcc1 : srcc0;
    const float* el = rel ? el1 : el0;
    const float* er = rel ? er1 : er0;
    int beg = offs[d], deg = offs[d + 1] - beg;
    float erh0 = er[d * 2], erh1 = er[d * 2 + 1];
    int fl = *flagp;

    int sr;
    float a0, a1, m0, i0, m1, i1;
    wave_softmax(srcc, beg, deg, el, erh0, erh1, lane, sr, a0, a1, m0, i0, m1, i1);

    auto xload = [&](int s, float v[4]) {
        if (fl) {
            float4 f = ((const float4*)x)[s * 32 + m];
            v[0] = f.x; v[1] = f.y; v[2] = f.z; v[3] = f.w;
        } else {
            uint2 pk = ((const uint2*)x)[s * 32 + m];
            v[0] = bf2f((bf16_t)(pk.x & 0xffffu));
            v[1] = bf2f((bf16_t)(pk.x >> 16));
            v[2] = bf2f((bf16_t)(pk.y & 0xffffu));
            v[3] = bf2f((bf16_t)(pk.y >> 16));
        }
    };
    float h0[4] = {}, h1[4] = {};   // head0/head1 x 4 cols
    {
        int dm = min(deg, 64);
        int T = (dm + 3) & ~3;
        for (int jj = slot; jj < T; jj += 4) {
            int j2 = jj + 2;
            int sA = __shfl(sr, jj), sB = __shfl(sr, j2);
            float pA0 = __shfl(a0, jj), pA1 = __shfl(a1, jj);
            float pB0 = __shfl(a0, j2), pB1 = __shfl(a1, j2);
            if (jj >= dm) { sA = 0; pA0 = 0.f; pA1 = 0.f; }
            if (j2 >= dm) { sB = 0; pB0 = 0.f; pB1 = 0.f; }
            float vA[4], vB[4];
            xload(sA, vA);
            xload(sB, vB);
#pragma unroll
            for (int k = 0; k < 4; ++k) {
                h0[k] += pA0 * vA[k] + pB0 * vB[k];
                h1[k] += pA1 * vA[k] + pB1 * vB[k];
            }
        }
        for (int jj = 64 + slot; jj < deg; jj += 2) {       // rare: deg > 64
            int sA = srcc[beg + jj];
            float2 ev = ((const float2*)el)[sA];
            float pA0 = exp2f(lrelu(ev.x + erh0) - m0) * i0;
            float pA1 = exp2f(lrelu(ev.y + erh1) - m1) * i1;
            float vA[4];
            xload(sA, vA);
#pragma unroll
            for (int k = 0; k < 4; ++k) {
                h0[k] += pA0 * vA[k];
                h1[k] += pA1 * vA[k];
            }
        }
    }
#pragma unroll
    for (int k = 0; k < 4; ++k) {
        h0[k] += __shfl_xor(h0[k], 32);
        h1[k] += __shfl_xor(h1[k], 32);
    }
    if (slot == 0) {
        bf16_t* yr = y1 + (size_t)d * 512 + rel * 256;
        uint2 u;
        u.x = pk2bf(h0[0], h0[1]); u.y = pk2bf(h0[2], h0[3]);
        ((uint2*)yr)[m] = u;
        u.x = pk2bf(h1[0], h1[1]); u.y = pk2bf(h1[2], h1[3]);
        ((uint2*)(yr + 128))[m] = u;
    }
}

// -------- gemm1: h1 = relu(y1 @ Wc1 + bc1); 8 col-frags/wave; el2/er2 -------
__global__ void gemm1_kernel(const bf16_t* __restrict__ A, const bf16_t* __restrict__ Wf,
                             const float* __restrict__ bc1, bf16_t* __restrict__ h1,
                             const float* __restrict__ wal2, const float* __restrict__ war2,
                             float* __restrict__ el2_0, float* __restrict__ er2_0,
                             float* __restrict__ el2_1, float* __restrict__ er2_1,
                             int n) {
    constexpr int K = 512, M = 256, KS = 16, NF = 8;
    int w = threadIdx.x >> 6, lane = threadIdx.x & 63;
    int q = lane >> 4, m16 = lane & 15;
    int rf = blockIdx.y * 64 + w * 16;
    if (rf >= n) return;
    f32x4 acc[NF] = {};
    const bf16_t* Arow = A + (size_t)(rf + m16) * K + q * 8;
    for (int ks = 0; ks < KS; ++ks) {
        short8 af = *(const short8*)(Arow + ks * 32);
#pragma unroll
        for (int f = 0; f < NF; ++f) {
            int ct = blockIdx.x * NF + f;
            short8 bfr = *(const short8*)(Wf + ((size_t)(ct * KS + ks) * 64 + lane) * 8);
            acc[f] = __builtin_amdgcn_mfma_f32_16x16x32_bf16(af, bfr, acc[f], 0, 0, 0);
        }
    }
    int col0 = blockIdx.x * (NF * 16);
    float del[2][2][4] = {};
    float der[2][2][4] = {};
#pragma unroll
    for (int f = 0; f < NF; ++f) {
        int col = col0 + f * 16 + m16;
        float bcv = bc1[col];
        float wle[2][2], wre[2][2];
#pragma unroll
        for (int rel = 0; rel < 2; ++rel)
#pragma unroll
            for (int h = 0; h < 2; ++h) {
                wle[rel][h] = wal2[(rel * 2 + h) * 256 + col];
                wre[rel][h] = war2[(rel * 2 + h) * 256 + col];
            }
#pragma unroll
        for (int r = 0; r < 4; ++r) {
            int row = rf + q * 4 + r;
            float v = fmaxf(acc[f][r] + bcv, 0.f);
            bf16_t hb = f2bf(v);
            h1[(size_t)row * M + col] = hb;
            float vb = bf2f(hb);
#pragma unroll
            for (int rel = 0; rel < 2; ++rel)
#pragma unroll
                for (int h = 0; h < 2; ++h) {
                    del[rel][h][r] += vb * wle[rel][h];
                    der[rel][h][r] += vb * wre[rel][h];
                }
        }
    }
#pragma unroll
    for (int off = 1; off < 16; off <<= 1) {
#pragma unroll
        for (int rel = 0; rel < 2; ++rel)
#pragma unroll
            for (int h = 0; h < 2; ++h)
#pragma unroll
                for (int r = 0; r < 4; ++r) {
                    del[rel][h][r] += __shfl_xor(del[rel][h][r], off);
                    der[rel][h][r] += __shfl_xor(der[rel][h][r], off);
                }
    }
    if (m16 == 0) {
#pragma unroll
        for (int r = 0; r < 4; ++r) {
            int row = rf + q * 4 + r;
            atomicAdd(&el2_0[row * 2 + 0], del[0][0][r]);
            atomicAdd(&el2_0[row * 2 + 1], del[0][1][r]);
            atomicAdd(&el2_1[row * 2 + 0], del[1][0][r]);
            atomicAdd(&el2_1[row * 2 + 1], del[1][1][r]);
            atomicAdd(&er2_0[row * 2 + 0], der[0][0][r]);
            atomicAdd(&er2_0[row * 2 + 1], der[0][1][r]);
            atomicAdd(&er2_1[row * 2 + 0], der[1][0][r]);
            atomicAdd(&er2_1[row * 2 + 1], der[1][1][r]);
        }
    }
}

// -------- gemmZ: z_rel = h1 @ (0.5*W2_rel); 8 col-frags/wave, grid.z=2 ------
__global__ void gemmz_kernel(const bf16_t* __restrict__ A, const bf16_t* __restrict__ Wzf,
                             bf16_t* __restrict__ z, int n) {
    constexpr int K = 256, M = 256, KS = 8, NF = 8;
    int rel = blockIdx.z;
    const bf16_t* Wf = Wzf + (size_t)rel * 65536;
    bf16_t* C = z + (size_t)rel * NN * 256;
    int w = threadIdx.x >> 6, lane = threadIdx.x & 63;
    int q = lane >> 4, m16 = lane & 15;
    int rf = blockIdx.y * 64 + w * 16;
    if (rf >= n) return;
    f32x4 acc[NF] = {};
    const bf16_t* Arow = A + (size_t)(rf + m16) * K + q * 8;
    for (int ks = 0; ks < KS; ++ks) {
        short8 af = *(const short8*)(Arow + ks * 32);
#pragma unroll
        for (int f = 0; f < NF; ++f) {
            int ct = blockIdx.x * NF + f;
            short8 bfr = *(const short8*)(Wf + ((size_t)(ct * KS + ks) * 64 + lane) * 8);
            acc[f] = __builtin_amdgcn_mfma_f32_16x16x32_bf16(af, bfr, acc[f], 0, 0, 0);
        }
    }
    int col0 = blockIdx.x * (NF * 16);
#pragma unroll
    for (int f = 0; f < NF; ++f) {
#pragma unroll
        for (int r = 0; r < 4; ++r) {
            int row = rf + q * 4 + r;
            C[(size_t)row * M + col0 + f * 16 + m16] = f2bf(acc[f][r]);
        }
    }
}

// -------- aggout: softmax + gather z rows -> out[N,128] ---------------------
// One wave per (dst node, relation). Half-wave (32 lanes x 8 cols, uint4)
// row gather; lane's head fixed by column range. rel0+rel1 combined via 2KB
// LDS + one barrier per 2-node block.
__global__ void aggout_kernel(
    const int* __restrict__ offs0, const int* __restrict__ srcc0,
    const float* __restrict__ el0, const float* __restrict__ er0,
    const int* __restrict__ offs1, const int* __restrict__ srcc1,
    const float* __restrict__ el1, const float* __restrict__ er1,
    const bf16_t* __restrict__ z, const float* __restrict__ bc2,
    void* __restrict__ out, const int* __restrict__ flagp) {
    __shared__ float sh[4][128];
    int t = threadIdx.x;
    int w = t >> 6, lane = t & 63;
    int slot = lane >> 5, m = lane & 31;
    int h = m >> 4;
    int d = blockIdx.x * 2 + (w >> 1);
    int rel = w & 1;
    const int* offs = rel ? offs1 : offs0;
    const int* srcc = rel ? srcc1 : srcc0;
    const float* el = rel ? el1 : el0;
    const float* er = rel ? er1 : er0;
    int beg = offs[d], deg = offs[d + 1] - beg;
    float erh0 = er[d * 2], erh1 = er[d * 2 + 1];

    int sr;
    float a0, a1, m0, i0, m1, i1;
    wave_softmax(srcc, beg, deg, el, erh0, erh1, lane, sr, a0, a1, m0, i0, m1, i1);

    float acc[8] = {};
    auto fmadd8 = [&](float a, uint4 p) {
        acc[0] += a * bf2f((bf16_t)(p.x & 0xffffu));
        acc[1] += a * bf2f((bf16_t)(p.x >> 16));
        acc[2] += a * bf2f((bf16_t)(p.y & 0xffffu));
        acc[3] += a * bf2f((bf16_t)(p.y >> 16));
        acc[4] += a * bf2f((bf16_t)(p.z & 0xffffu));
        acc[5] += a * bf2f((bf16_t)(p.z >> 16));
        acc[6] += a * bf2f((bf16_t)(p.w & 0xffffu));
        acc[7] += a * bf2f((bf16_t)(p.w >> 16));
    };
    {
        const uint4* zp = (const uint4*)(z + (size_t)rel * NN * 256);
        int dm = min(deg, 64);
        int T = (dm + 3) & ~3;
        for (int jj = slot; jj < T; jj += 4) {
            int j2 = jj + 2;
            int sA = __shfl(sr, jj), sB = __shfl(sr, j2);
            float xA0 = __shfl(a0, jj), xA1 = __shfl(a1, jj);
            float xB0 = __shfl(a0, j2), xB1 = __shfl(a1, j2);
            float aA = h ? xA1 : xA0;
            float aB = h ? xB1 : xB0;
            if (jj >= dm) { sA = 0; aA = 0.f; }
            if (j2 >= dm) { sB = 0; aB = 0.f; }
            uint4 pA = zp[sA * 32 + m];
            uint4 pB = zp[sB * 32 + m];
            fmadd8(aA, pA);
            fmadd8(aB, pB);
        }
        for (int jj = 64 + slot; jj < deg; jj += 2) {       // rare: deg > 64
            int sA = srcc[beg + jj];
            float2 ev = ((const float2*)el)[sA];
            float aA = h ? (exp2f(lrelu(ev.y + erh1) - m1) * i1)
                         : (exp2f(lrelu(ev.x + erh0) - m0) * i0);
            uint4 pA = zp[sA * 32 + m];
            fmadd8(aA, pA);
        }
    }
    // combine edge slots, then heads: lane m<16 of slot0 holds cols m*8..m*8+7
#pragma unroll
    for (int k = 0; k < 8; ++k) acc[k] += __shfl_xor(acc[k], 32);
#pragma unroll
    for (int k = 0; k < 8; ++k) acc[k] += __shfl_xor(acc[k], 16);
    if (slot == 0 && m < 16) {
#pragma unroll
        for (int k = 0; k < 8; ++k) sh[w][m * 8 + k] = acc[k];
    }
    __syncthreads();
    // 256 threads: t<128 -> node 0 of the pair, t>=128 -> node 1
    int ni = t >> 7;
    int o = t & 127;
    int dd = blockIdx.x * 2 + ni;
    float v = bc2[o] + sh[ni * 2][o] + sh[ni * 2 + 1][o];
    if (*flagp) ((float*)out)[(size_t)dd * 128 + o] = v;
    else        ((bf16_t*)out)[(size_t)dd * 128 + o] = f2bf(v);
}

extern "C" void kernel_launch(void* const* d_in, const int* in_sizes, int n_in,
                              void* d_out, int out_size, void* d_ws, size_t ws_size,
                              hipStream_t stream) {
    (void)in_sizes; (void)n_in; (void)out_size; (void)ws_size;
    const void* x0 = d_in[0];
    const int* src0 = (const int*)d_in[1];
    const int* dst0 = (const int*)d_in[2];
    const int* src1 = (const int*)d_in[3];
    const int* dst1 = (const int*)d_in[4];

    char* ws = (char*)d_ws;
    size_t off = 0;
    auto alloc = [&](size_t bytes) -> void* {
        void* p = ws + off;
        off = (off + bytes + 255) & ~(size_t)255;
        return p;
    };
    int* flag = (int*)alloc(4);
    static const int tn[NTC] = {128 * 512, 512, 512, 512,
                                128 * 512, 512, 512, 512,
                                256 * 256, 256, 256, 256,
                                256 * 256, 256, 256, 256};
    bf16_t* tb[NTC];
    for (int i = 0; i < NTC; ++i) tb[i] = (bf16_t*)alloc((size_t)tn[i] * 2);

    bf16_t* Wc1f = (bf16_t*)alloc((size_t)512 * 256 * 2);
    bf16_t* Wzf  = (bf16_t*)alloc((size_t)2 * 65536 * 2);
    float* wal1 = (float*)alloc(512 * 4);
    float* war1 = (float*)alloc(512 * 4);
    float* wal2 = (float*)alloc(1024 * 4);
    float* war2 = (float*)alloc(1024 * 4);
    float* bc1  = (float*)alloc(256 * 4);
    float* bc2  = (float*)alloc(128 * 4);

    char* zbeg = ws + off;
    int* cnt0 = (int*)alloc(NN * 4);
    int* cnt1 = (int*)alloc(NN * 4);
    float* el2_0 = (float*)alloc(NN * 2 * 4);
    float* er2_0 = (float*)alloc(NN * 2 * 4);
    float* el2_1 = (float*)alloc(NN * 2 * 4);
    float* er2_1 = (float*)alloc(NN * 2 * 4);
    char* zend = ws + off;
    int zcount = (int)((zend - zbeg) >> 2);

    int* offs0 = (int*)alloc((NN + 1) * 4);
    int* offs1 = (int*)alloc((NN + 1) * 4);
    int* npfx0 = (int*)alloc(NN * 4);
    int* npfx1 = (int*)alloc(NN * 4);
    int* bsum0 = (int*)alloc(128 * 4);
    int* bsum1 = (int*)alloc(128 * 4);
    int* rank0 = (int*)alloc(NE * 4);
    int* rank1 = (int*)alloc(NE * 4);
    int* srcc0 = (int*)alloc(NE * 4);
    int* srcc1 = (int*)alloc(NE * 4);
    float* el1_0 = (float*)alloc(NN * 2 * 4);
    float* er1_0 = (float*)alloc(NN * 2 * 4);
    float* el1_1 = (float*)alloc(NN * 2 * 4);
    float* er1_1 = (float*)alloc(NN * 2 * 4);
    bf16_t* h1 = (bf16_t*)alloc((size_t)NN * 256 * 2);
    bf16_t* Y  = (bf16_t*)alloc((size_t)NN * 1024 * 2);  // y1 [N,512]; later z [2][N,256]
    bf16_t* y1 = Y;
    bf16_t* z  = Y;   // safe: gemmZ writes z after gemm1 finished reading y1

    // ---- 1. convert weights + zero + inline dtype detect ----
    CzArgs cz;
    static const int din_idx[NTC] = {5, 6, 7, 8, 9, 10, 11, 12,
                                     13, 14, 15, 16, 17, 18, 19, 20};
    int total_blocks = 0;
    for (int i = 0; i < NTC; ++i) {
        cz.src[i] = d_in[din_idx[i]];
        cz.dst[i] = tb[i];
        cz.n[i] = tn[i];
        cz.nblk[i] = (tn[i] + 255) / 256;
        total_blocks += cz.nblk[i];
    }
    cz.zero_ptr = (int*)zbeg;
    cz.zn = zcount;
    cz.nblk[NTC] = (zcount + 255) / 256;
    total_blocks += cz.nblk[NTC];
    cz.xsrc = (const unsigned*)x0;
    cz.flag_out = flag;
    convzero_kernel<<<total_blocks, 256, 0, stream>>>(cz);

    // ---- 2. prep + hist (hist stores rank = atomic return) ----
    PhArgs ph;
    ph.p.W1[0] = tb[0];  ph.p.W1[1] = tb[4];
    ph.p.W2[0] = tb[8];  ph.p.W2[1] = tb[12];
    ph.p.al1[0] = tb[1]; ph.p.ar1[0] = tb[2];
    ph.p.al1[1] = tb[5]; ph.p.ar1[1] = tb[6];
    ph.p.al2[0] = tb[9]; ph.p.ar2[0] = tb[10];
    ph.p.al2[1] = tb[13]; ph.p.ar2[1] = tb[14];
    ph.p.b1[0] = tb[3];  ph.p.b1[1] = tb[7];
    ph.p.b2[0] = tb[11]; ph.p.b2[1] = tb[15];
    ph.p.wal1 = wal1; ph.p.war1 = war1;
    ph.p.wal2 = wal2; ph.p.war2 = war2;
    ph.p.bc1 = bc1; ph.p.bc2 = bc2;
    ph.p.Wc1f = Wc1f; ph.p.Wzf = Wzf;
    ph.c.src[0] = src0; ph.c.src[1] = src1;
    ph.c.dst[0] = dst0; ph.c.dst[1] = dst1;
    ph.c.cnt[0] = cnt0; ph.c.cnt[1] = cnt1;
    ph.c.offs[0] = offs0; ph.c.offs[1] = offs1;
    ph.c.rank[0] = rank0; ph.c.rank[1] = rank1;
    ph.c.srcc[0] = srcc0; ph.c.srcc[1] = srcc1;
    ph.c.npfx[0] = npfx0; ph.c.npfx[1] = npfx1;
    ph.c.bsum[0] = bsum0; ph.c.bsum[1] = bsum1;
    prep_hist_kernel<<<142 + 2500, 256, 0, stream>>>(ph);

    // ---- 3. hierarchical coalesced scan ----
    scan_blk_kernel<<<dim3(NB, 2), 256, 0, stream>>>(ph.c);
    scan_top_kernel<<<2, 128, 0, stream>>>(ph.c);
    scan_fin_kernel<<<dim3(NB, 2), 256, 0, stream>>>(ph.c);

    // ---- 4. elr1 (8 nodes/wave) + atomic-free scatter ----
    scat_elr_kernel<<<625 + 626, 256, 0, stream>>>(
        ph.c, x0, flag, wal1, war1, el1_0, er1_0, el1_1, er1_1);

    // ---- 5. agg1: gather x rows -> y1[N,512] ----
    agg1_kernel<<<10000, 256, 0, stream>>>(offs0, srcc0, el1_0, er1_0,
                                           offs1, srcc1, el1_1, er1_1, x0, flag, y1);

    // ---- 6. gemm1 -> h1, el2/er2 ----
    gemm1_kernel<<<dim3(2, 313), 256, 0, stream>>>(
        y1, Wc1f, bc1, h1, wal2, war2, el2_0, er2_0, el2_1, er2_1, NN);

    // ---- 7. gemmZ: z_rel = h1 @ (0.5*W2_rel) ----
    gemmz_kernel<<<dim3(2, 313, 2), 256, 0, stream>>>(h1, Wzf, z, NN);

    // ---- 8. aggout: gather z rows -> d_out ----
    aggout_kernel<<<10000, 256, 0, stream>>>(offs0, srcc0, el2_0, er2_0,
                                             offs1, srcc1, el2_1, er2_1,
                                             z, bc2, d_out, flag);
}